// Round 6
// baseline (161.303 us; speedup 1.0000x reference)
//
#include <hip/hip_runtime.h>
#include <math.h>

#define C 64
#define NHEADS 4
#define DH 16
#define NN 262144   // H*W
#define NB 2
#define PB 512      // partial Gram blocks per batch
#define NT 2        // 256-col tiles per block (gram)
#define EPS 1e-12f

typedef __attribute__((ext_vector_type(8))) short short8v;     // 8 bf16
typedef __attribute__((ext_vector_type(8))) unsigned short ushort8v;
typedef __attribute__((ext_vector_type(4))) unsigned short ushort4v;
typedef __attribute__((ext_vector_type(4))) float f32x4;

static __device__ __forceinline__ unsigned short f2bf(float f) {
  union { float f; unsigned int u; } v; v.f = f;
  unsigned int r = v.u + 0x7fffu + ((v.u >> 16) & 1u);   // RNE round to bf16
  return (unsigned short)(r >> 16);
}

// ---------------- K1: per-batch partial Gram via MFMA ----------------
// grid (PB, NB), 256 threads = 4 waves, 3 blocks/CU. Block covers NT*256 cols.
// T14 reg-staged prefetch: next tile's global loads issue before the MFMA
// phase and stay in flight across a RAW s_barrier (only lgkmcnt drained) —
// __syncthreads would drain vmcnt(0) and kill the overlap.
// LDS tile: bf16 [64][256], 16B slot s of row c stored at (s ^ (c&7)).
__global__ __launch_bounds__(256, 3) void gram_kernel(const float* __restrict__ x,
                                                      float* __restrict__ Gc) {
  __shared__ unsigned short xs[C * 256];
  const int b = blockIdx.y;
  const int chunk = blockIdx.x;
  const float* xb = x + (size_t)b * C * NN;
  const int t = threadIdx.x;
  const int w = t >> 6, l = t & 63;
  const int lrow = l & 15, lhi = l >> 4;
  const int sc = t >> 5, soct = t & 31;    // staging: row-group / octet

  const int gA0 = (w >> 1) * 2, gA1 = gA0 + 1;
  const int gB0 = (w & 1) * 2,  gB1 = gB0 + 1;
  const int cA0 = gA0 * 16 + lrow, cA1 = gA1 * 16 + lrow;
  const int cB0 = gB0 * 16 + lrow, cB1 = gB1 * 16 + lrow;

  f32x4 acc0 = {0.f,0.f,0.f,0.f}, acc1 = {0.f,0.f,0.f,0.f};
  f32x4 acc2 = {0.f,0.f,0.f,0.f}, acc3 = {0.f,0.f,0.f,0.f};

  float4 pre[8][2];
  // prologue: load tile 0
#pragma unroll
  for (int i = 0; i < 8; ++i) {
    const int c = i * 8 + sc;
    const float* src = xb + (size_t)c * NN + chunk * (NT * 256) + soct * 8;
    pre[i][0] = *reinterpret_cast<const float4*>(src);
    pre[i][1] = *reinterpret_cast<const float4*>(src + 4);
  }

  for (int tile = 0; tile < NT; ++tile) {
    // pack staged regs -> LDS
#pragma unroll
    for (int i = 0; i < 8; ++i) {
      const int c = i * 8 + sc;
      ushort8v pk;
      pk[0] = f2bf(pre[i][0].x); pk[1] = f2bf(pre[i][0].y);
      pk[2] = f2bf(pre[i][0].z); pk[3] = f2bf(pre[i][0].w);
      pk[4] = f2bf(pre[i][1].x); pk[5] = f2bf(pre[i][1].y);
      pk[6] = f2bf(pre[i][1].z); pk[7] = f2bf(pre[i][1].w);
      *reinterpret_cast<ushort8v*>(&xs[c * 256 + ((soct ^ (c & 7)) << 3)]) = pk;
    }
    // issue next-tile loads (in flight across the barrier + MFMA phase)
    if (tile + 1 < NT) {
      const int j0 = chunk * (NT * 256) + (tile + 1) * 256;
#pragma unroll
      for (int i = 0; i < 8; ++i) {
        const int c = i * 8 + sc;
        const float* src = xb + (size_t)c * NN + j0 + soct * 8;
        pre[i][0] = *reinterpret_cast<const float4*>(src);
        pre[i][1] = *reinterpret_cast<const float4*>(src + 4);
      }
    }
    asm volatile("s_waitcnt lgkmcnt(0)" ::: "memory");  // LDS writes visible
    __builtin_amdgcn_s_barrier();                       // raw: vmcnt stays
#pragma unroll
    for (int s = 0; s < 8; ++s) {
      const int o = s * 4 + lhi;
      const short8v fA0 = *reinterpret_cast<const short8v*>(&xs[cA0 * 256 + ((o ^ (cA0 & 7)) << 3)]);
      const short8v fA1 = *reinterpret_cast<const short8v*>(&xs[cA1 * 256 + ((o ^ (cA1 & 7)) << 3)]);
      const short8v fB0 = *reinterpret_cast<const short8v*>(&xs[cB0 * 256 + ((o ^ (cB0 & 7)) << 3)]);
      const short8v fB1 = *reinterpret_cast<const short8v*>(&xs[cB1 * 256 + ((o ^ (cB1 & 7)) << 3)]);
      acc0 = __builtin_amdgcn_mfma_f32_16x16x32_bf16(fA0, fB0, acc0, 0, 0, 0);
      acc1 = __builtin_amdgcn_mfma_f32_16x16x32_bf16(fA0, fB1, acc1, 0, 0, 0);
      acc2 = __builtin_amdgcn_mfma_f32_16x16x32_bf16(fA1, fB0, acc2, 0, 0, 0);
      acc3 = __builtin_amdgcn_mfma_f32_16x16x32_bf16(fA1, fB1, acc3, 0, 0, 0);
    }
    asm volatile("s_waitcnt lgkmcnt(0)" ::: "memory");  // reads done (WAR)
    __builtin_amdgcn_s_barrier();
  }
  // C/D layout: col = lane&15, row = (lane>>4)*4 + reg
  float* g = Gc + ((size_t)b * PB + chunk) * 4096;
#pragma unroll
  for (int r = 0; r < 4; ++r) {
    const int row = lhi * 4 + r;
    g[(gA0 * 16 + row) * 64 + gB0 * 16 + lrow] = acc0[r];
    g[(gA0 * 16 + row) * 64 + gB1 * 16 + lrow] = acc1[r];
    g[(gA1 * 16 + row) * 64 + gB0 * 16 + lrow] = acc2[r];
    g[(gA1 * 16 + row) * 64 + gB1 * 16 + lrow] = acc3[r];
  }
}

// ---------------- K1b: tree-reduce the PB partials -> G[b][4096] ----------------
__global__ __launch_bounds__(256) void reduce_kernel(const float* __restrict__ Gc,
                                                     float* __restrict__ G) {
  __shared__ float s[4][64];
  const int b = blockIdx.y;
  const int g = blockIdx.x;
  const int t = threadIdx.x;
  const int e = g * 64 + (t & 63);
  const int chunk = t >> 6;
  float sum = 0.f;
  for (int p = chunk; p < PB; p += 4)
    sum += Gc[((size_t)b * PB + p) * 4096 + e];
  s[chunk][t & 63] = sum;
  __syncthreads();
  if (t < 64) G[(size_t)b * 4096 + g * 64 + t] = s[0][t] + s[1][t] + s[2][t] + s[3][t];
}

// ---------------- K2: attention math -> E (bf16, includes +I) ----------------
__global__ __launch_bounds__(256) void attn_kernel(const float* __restrict__ G,
    const float* __restrict__ Wq, const float* __restrict__ Wk,
    const float* __restrict__ Wv, const float* __restrict__ Wp,
    const float* __restrict__ rescale, unsigned short* __restrict__ Ebf) {
  __shared__ float Gs[4096], GQt[4096], GKt[4096], T[4096];
  __shared__ float attnw[64][DH];
  __shared__ float nq[64], nk[64];
  const int b = blockIdx.x;
  const int t = threadIdx.x;

  for (int i = t; i < 4096; i += 256) Gs[i] = G[(size_t)b * 4096 + i];
  __syncthreads();
  for (int i = t; i < 4096; i += 256) {
    const int c = i >> 6, e = i & 63;
    float sq_ = 0.f, sk_ = 0.f;
    for (int c2 = 0; c2 < 64; ++c2) {
      const float g = Gs[c * 64 + c2];
      sq_ += g * Wq[e * 64 + c2];
      sk_ += g * Wk[e * 64 + c2];
    }
    GQt[c * 64 + e] = sq_;
    GKt[c * 64 + e] = sk_;
  }
  __syncthreads();
  if (t < 64) {
    float s = 0.f;
    for (int c2 = 0; c2 < 64; ++c2) s += Wq[t * 64 + c2] * GQt[c2 * 64 + t];
    nq[t] = sqrtf(fmaxf(s, 0.f));
  } else if (t < 128) {
    const int d = t - 64;
    float s = 0.f;
    for (int c2 = 0; c2 < 64; ++c2) s += Wk[d * 64 + c2] * GKt[c2 * 64 + d];
    nk[d] = sqrtf(fmaxf(s, 0.f));
  }
  __syncthreads();
  if (t < 64) {
    const int h = t >> 4;
    const float rs = rescale[h];
    const float nkd = fmaxf(nk[t], EPS);
    float logits[DH];
    float mx = -1e30f;
    for (int ee = 0; ee < DH; ++ee) {
      const int e = h * DH + ee;
      float num = 0.f;
      for (int c2 = 0; c2 < 64; ++c2) num += Wk[t * 64 + c2] * GQt[c2 * 64 + e];
      const float l = num / (nkd * fmaxf(nq[e], EPS)) * rs;
      logits[ee] = l;
      mx = fmaxf(mx, l);
    }
    float sum = 0.f;
    for (int ee = 0; ee < DH; ++ee) { const float p = expf(logits[ee] - mx); logits[ee] = p; sum += p; }
    const float inv = 1.f / sum;
    for (int ee = 0; ee < DH; ++ee) attnw[t][ee] = logits[ee] * inv;
  }
  __syncthreads();
  for (int i = t; i < 4096; i += 256) {
    const int r = i >> 6, c = i & 63;
    const int h = r >> 4;
    float s = 0.f;
    for (int e = 0; e < DH; ++e) s += attnw[r][e] * Wv[(h * DH + e) * 64 + c];
    T[i] = s;
  }
  __syncthreads();
  for (int i = t; i < 4096; i += 256) {
    const int r = i >> 6, c = i & 63;
    float s = (r == c) ? 1.f : 0.f;
    for (int m = 0; m < 64; ++m) s += Wp[r * 64 + m] * T[m * 64 + c];
    Ebf[(size_t)b * 4096 + i] = f2bf(s);
  }
}

// ---------------- K3: out = E * x + bp via MFMA ----------------
// grid (2048, NB), 256 threads = 4 waves, 4 blocks/CU. Block = 64o x 128n.
// Operands SWAPPED vs R5: acc = mfma(A=xfrag, B=Efrag) -> D[n][o]; each lane
// then holds 4 consecutive n for one o -> float4 stores (was 32 scalar dwords).
__global__ __launch_bounds__(256, 4) void apply_kernel(const float* __restrict__ x,
    const unsigned short* __restrict__ Ebf, const float* __restrict__ bp,
    float* __restrict__ out) {
  __shared__ unsigned short xt[128 * 64];   // [n][c] bf16, swizzled
  const int b = blockIdx.y;
  const int n0 = blockIdx.x * 128;
  const float* xb = x + (size_t)b * C * NN;
  float* ob = out + (size_t)b * C * NN;
  const int t = threadIdx.x;
  const int w = t >> 6, l = t & 63;
  const int lrow = l & 15, lhi = l >> 4;

  // E fragments: ef[ot][ks] = E[ot*16 + lrow][ks*32 + lhi*8 .. +7]
  // (B-operand: col=lane&15 -> o, value = E[o][k])
  short8v ef[4][2];
  const unsigned short* eb = Ebf + (size_t)b * 4096;
#pragma unroll
  for (int ot = 0; ot < 4; ++ot)
#pragma unroll
    for (int ks = 0; ks < 2; ++ks)
      ef[ot][ks] = *reinterpret_cast<const short8v*>(eb + (ot * 16 + lrow) * 64 + ks * 32 + lhi * 8);

  // stage x transposed: wave w covers c in [w*16, w*16+16), lane covers n = h*64+l
#pragma unroll
  for (int h = 0; h < 2; ++h) {
    const int n = h * 64 + l;
#pragma unroll
    for (int i = 0; i < 4; ++i) {
      const int c0 = w * 16 + i * 4;
      const float v0 = xb[(size_t)(c0 + 0) * NN + n0 + n];
      const float v1 = xb[(size_t)(c0 + 1) * NN + n0 + n];
      const float v2 = xb[(size_t)(c0 + 2) * NN + n0 + n];
      const float v3 = xb[(size_t)(c0 + 3) * NN + n0 + n];
      ushort4v pk;
      pk[0] = f2bf(v0); pk[1] = f2bf(v1); pk[2] = f2bf(v2); pk[3] = f2bf(v3);
      const int q = c0 >> 2;   // 8B-quad index 0..15
      *reinterpret_cast<ushort4v*>(
          &xt[n * 64 + ((((q >> 1) ^ (n & 7)) << 3) + (q & 1) * 4)]) = pk;
    }
  }
  __syncthreads();

  // MFMA: wave w owns n-range [w*32, w*32+32) = 2 n-tiles; 4 o-tiles each.
  f32x4 acc[4][2];
#pragma unroll
  for (int ot = 0; ot < 4; ++ot)
#pragma unroll
    for (int nn = 0; nn < 2; ++nn) acc[ot][nn] = (f32x4){0.f, 0.f, 0.f, 0.f};

  const int nbase = w * 32;
#pragma unroll
  for (int nn = 0; nn < 2; ++nn) {
    const int n = nbase + nn * 16 + lrow;   // A-row this lane carries
#pragma unroll
    for (int ks = 0; ks < 2; ++ks) {
      const int s = ks * 4 + lhi;           // logical 16B slot (k = s*8..s*8+7)
      const short8v xf = *reinterpret_cast<const short8v*>(&xt[n * 64 + ((s ^ (n & 7)) << 3)]);
#pragma unroll
      for (int ot = 0; ot < 4; ++ot)
        acc[ot][nn] = __builtin_amdgcn_mfma_f32_16x16x32_bf16(xf, ef[ot][ks], acc[ot][nn], 0, 0, 0);
    }
  }

  // store: D[n][o] layout -> lane: o = ot*16 + lrow, n = nbase + nn*16 + lhi*4 + r
#pragma unroll
  for (int ot = 0; ot < 4; ++ot) {
    const int o = ot * 16 + lrow;
    const float bias = bp[o];
#pragma unroll
    for (int nn = 0; nn < 2; ++nn) {
      const int nb4 = nbase + nn * 16 + lhi * 4;
      float4 o4;
      o4.x = acc[ot][nn][0] + bias;
      o4.y = acc[ot][nn][1] + bias;
      o4.z = acc[ot][nn][2] + bias;
      o4.w = acc[ot][nn][3] + bias;
      *reinterpret_cast<float4*>(&ob[(size_t)o * NN + n0 + nb4]) = o4;
    }
  }
}

extern "C" void kernel_launch(void* const* d_in, const int* in_sizes, int n_in,
                              void* d_out, int out_size, void* d_ws, size_t ws_size,
                              hipStream_t stream) {
  const float* x       = (const float*)d_in[0];
  const float* Wq      = (const float*)d_in[1];
  const float* Wk      = (const float*)d_in[2];
  const float* Wv      = (const float*)d_in[3];
  const float* Wp      = (const float*)d_in[4];
  const float* bp      = (const float*)d_in[5];
  const float* rescale = (const float*)d_in[6];
  float* out = (float*)d_out;

  // ws (~512 MB per poison-fill evidence): partials 16.8 MB + G + E
  float* Gc = (float*)d_ws;                          // NB*PB*4096 f32
  float* G  = Gc + (size_t)NB * PB * 4096;           // NB*4096 f32
  unsigned short* Ebf = (unsigned short*)(G + (size_t)NB * 4096);  // NB*4096 bf16

  gram_kernel<<<dim3(PB, NB), dim3(256), 0, stream>>>(x, Gc);
  reduce_kernel<<<dim3(64, NB), dim3(256), 0, stream>>>(Gc, G);
  attn_kernel<<<dim3(NB), dim3(256), 0, stream>>>(G, Wq, Wk, Wv, Wp, rescale, Ebf);
  apply_kernel<<<dim3(2048, NB), dim3(256), 0, stream>>>(x, Ebf, bp, out);
}